// Round 12
// baseline (509.402 us; speedup 1.0000x reference)
//
#include <hip/hip_runtime.h>
#include <hip/hip_bf16.h>
#include <hip/hip_fp16.h>

constexpr int FDIM = 128;
#define HSCALE 16384.0f         // 2^14: |h|<1 -> scaled <16384 <= 65504, always safe
#define HSCALE_INV (1.0f/16384.0f)
#define ZSCALE 0.125f           // extra headroom for Zh = Hh @ W6
#define ZSCALE_COMP (HSCALE_INV * 8.0f)

typedef _Float16 f16x8 __attribute__((ext_vector_type(8)));
typedef float f32x4 __attribute__((ext_vector_type(4)));
typedef unsigned long long ull;

// ===================== atomic-reserved CSR build (2 partition passes) =====================
// record: [col:17 @47][row:17 @30][ew_f16 @0]
constexpr int CHUNK = 4096;
constexpr int B1 = 64;
constexpr int B2 = 64;
constexpr int NGRP = B1 * B2;   // 4096
constexpr int MAXC2 = 20;

__global__ __launch_bounds__(256) void k_init(int* __restrict__ cur1,
                                              int* __restrict__ cur2,
                                              int* __restrict__ gtot,
                                              int cap1, int cap2)
{
    int i = blockIdx.x * 256 + threadIdx.x;
    if (i < B1) cur1[i] = i * cap1;
    if (i < NGRP) cur2[i] = i * cap2;
    if (i == 0) gtot[0] = 0;
}

// pass 1: chunk -> 64 coarse buckets.
__global__ __launch_bounds__(256) void k_p1part(const int* __restrict__ col,
                                                const int* __restrict__ row,
                                                const float* __restrict__ ew,
                                                int* __restrict__ cur1,
                                                ull* __restrict__ rec1, int E)
{
    __shared__ ull stage[CHUNK];
    __shared__ int hcnt[B1], lb[B1], gb[B1], lcur[B1];
    int blk = blockIdx.x, t = threadIdx.x;
    if (t < B1) hcnt[t] = 0;
    __syncthreads();
    int base = blk * CHUNK;
    ull rc[16];
    #pragma unroll
    for (int it = 0; it < 16; ++it) {
        int g = base + it * 256 + t;
        if (g < E) {
            int c = col[g], r = row[g];
            rc[it] = ((ull)c << 47) | ((ull)r << 30) |
                     (ull)__half_as_ushort(__float2half(ew[g]));
            atomicAdd(&hcnt[c >> 11], 1);
        } else rc[it] = ~0ull;
    }
    __syncthreads();
    if (t == 0) {
        int run = 0;
        for (int b = 0; b < B1; ++b) { lb[b] = run; run += hcnt[b]; }
    }
    __syncthreads();
    if (t < B1) { lcur[t] = lb[t]; gb[t] = atomicAdd(&cur1[t], hcnt[t]); }
    __syncthreads();
    #pragma unroll
    for (int it = 0; it < 16; ++it) {
        if (rc[it] != ~0ull) {
            int b = (int)(rc[it] >> 58);
            stage[atomicAdd(&lcur[b], 1)] = rc[it];
        }
    }
    __syncthreads();
    int here = min(CHUNK, E - base);
    for (int j = t; j < here; j += 256) {
        ull v = stage[j];
        int b = (int)(v >> 58);
        rec1[gb[b] + (j - lb[b])] = v;
    }
}

// pass 2: within each coarse bucket, partition chunks into 64 sub-buckets (groups).
__global__ __launch_bounds__(256) void k_p2part(const ull* __restrict__ rec1,
                                                const int* __restrict__ cur1,
                                                int* __restrict__ cur2,
                                                ull* __restrict__ rec2,
                                                int cap1)
{
    __shared__ ull stage[CHUNK];
    __shared__ int hcnt[B2], lb[B2], gb[B2], lcur[B2];
    int b = blockIdx.x / MAXC2, ci = blockIdx.x % MAXC2, t = threadIdx.x;
    int S1 = b * cap1;
    int size = cur1[b] - S1;
    for (int c = ci; c * CHUNK < size; c += MAXC2) {
        int cb = S1 + c * CHUNK;
        int m = min(CHUNK, size - c * CHUNK);
        __syncthreads();
        if (t < B2) hcnt[t] = 0;
        __syncthreads();
        ull rc[16];
        #pragma unroll
        for (int it = 0; it < 16; ++it) {
            int j = it * 256 + t;
            if (j < m) {
                ull v = rec1[cb + j];
                rc[it] = v;
                atomicAdd(&hcnt[(int)((v >> 52) & 63)], 1);
            } else rc[it] = ~0ull;
        }
        __syncthreads();
        if (t == 0) {
            int run = 0;
            for (int s = 0; s < B2; ++s) { lb[s] = run; run += hcnt[s]; }
        }
        __syncthreads();
        if (t < B2) { lcur[t] = lb[t]; gb[t] = atomicAdd(&cur2[b * B2 + t], hcnt[t]); }
        __syncthreads();
        #pragma unroll
        for (int it = 0; it < 16; ++it) {
            if (rc[it] != ~0ull) {
                int s = (int)((rc[it] >> 52) & 63);
                stage[atomicAdd(&lcur[s], 1)] = rc[it];
            }
        }
        __syncthreads();
        for (int j = t; j < m; j += 256) {
            ull v = stage[j];
            int s = (int)((v >> 52) & 63);
            rec2[gb[s] + (j - lb[s])] = v;
        }
    }
}

// final: counting sort per 32-node group, records register-resident (single read).
// Compact ep base reserved via one global atomicAdd per group (arrival-ordered
// regions; per-node (start,end) stored in off2 so cross-group order is irrelevant).
__global__ __launch_bounds__(256) void k_p3(const ull* __restrict__ rec2,
                                            const int* __restrict__ cur2,
                                            int* __restrict__ gtot,
                                            int2* __restrict__ ep, int2* __restrict__ off2,
                                            float* __restrict__ dis, int cap2, int N)
{
    __shared__ int h[32], lb[32], cur[32];
    __shared__ float dg[32], sdis[32];
    __shared__ int sbase;
    int g = blockIdx.x, t = threadIdx.x;
    int S1 = g * cap2;
    int size = cur2[g] - S1;
    if (t < 32) { h[t] = 0; dg[t] = 0.f; }
    __syncthreads();
    ull rc[8];                      // cap2 <= 2048 = 256*8
    #pragma unroll
    for (int it = 0; it < 8; ++it) {
        int j = it * 256 + t;
        if (j < size) {
            ull v = rec2[S1 + j];
            rc[it] = v;
            int nl = (int)((v >> 47) & 31);
            atomicAdd(&h[nl], 1);
            atomicAdd(&dg[nl], __half2float(__ushort_as_half((unsigned short)(v & 0xFFFF))));
        } else rc[it] = ~0ull;
    }
    __syncthreads();
    if (t == 0) {
        sbase = atomicAdd(gtot, size);
        int run = 0;
        for (int k = 0; k < 32; ++k) { lb[k] = run; run += h[k]; }
    }
    __syncthreads();
    if (t < 32) {
        int b0 = sbase + lb[t];
        cur[t] = b0;
        sdis[t] = 1.0f / sqrtf(dg[t] + 1.0f);   // self-loop included; >= 1 always
        int node = g * 32 + t;
        if (node < N) { off2[node] = make_int2(b0, b0 + h[t]); dis[node] = sdis[t]; }
    }
    __syncthreads();
    #pragma unroll
    for (int it = 0; it < 8; ++it) {
        if (rc[it] != ~0ull) {
            int nl = (int)((rc[it] >> 47) & 31);
            int p = atomicAdd(&cur[nl], 1);
            float w = __half2float(__ushort_as_half((unsigned short)(rc[it] & 0xFFFF))) * sdis[nl];
            ep[p] = make_int2((int)((rc[it] >> 30) & 0x1FFFF), __float_as_int(w));
        }
    }
}

// ---------------- fused prep: h0 f32->f16 with dis pre-scale  +  6 W transposes ----------------
__global__ __launch_bounds__(256) void k_prep(const float4* __restrict__ in,
                                              const float* __restrict__ dis, __half2* __restrict__ out, int n4,
                                              const float* __restrict__ W1, const float* __restrict__ W2,
                                              const float* __restrict__ W3, const float* __restrict__ W4,
                                              const float* __restrict__ W5, const float* __restrict__ W6,
                                              __half* __restrict__ T1, __half* __restrict__ T2,
                                              __half* __restrict__ T3, __half* __restrict__ T4,
                                              __half* __restrict__ T5, __half* __restrict__ T6,
                                              int cvtBlocks)
{
    if ((int)blockIdx.x < cvtBlocks) {
        int i = blockIdx.x * 256 + threadIdx.x;
        if (i >= n4) return;
        float4 v = in[i];
        float d = dis[i >> 5];          // 32 float4 per row
        __half2 a = __floats2half2_rn(v.x * d, v.y * d);
        __half2 b = __floats2half2_rn(v.z * d, v.w * d);
        float2 pk;
        ((__half2*)&pk)[0] = a;
        ((__half2*)&pk)[1] = b;
        *(float2*)&out[(size_t)i * 2] = pk;
    } else {
        int idx = (blockIdx.x - cvtBlocks) * 256 + threadIdx.x;
        const float* W; __half* T; int local, nf;
        if (idx < 81920) {
            int seg = idx >> 14;
            local = idx & 16383;
            nf = 128;
            const float* Ws[5] = {W1, W2, W3, W4, W5};
            __half* Ts[5] = {T1, T2, T3, T4, T5};
            W = Ws[seg]; T = Ts[seg];
        } else if (idx < 90112) {
            local = idx - 81920;
            nf = 64;
            W = W6; T = T6;
        } else return;
        int n = local >> 7, k = local & 127;
        T[local] = __float2half(W[(size_t)k * nf + n]);
    }
}

// ---------------- SpMM: Yh = fp16(aggregate), round-8 proven (4-wide, 2-deep) ----------------
__global__ __launch_bounds__(256) void k_spmm(const __half2* __restrict__ Xh,
                                              const int2* __restrict__ ep,
                                              const int2* __restrict__ off2,
                                              const float* __restrict__ dis,
                                              __half2* __restrict__ Yh, int n)
{
    int gt = blockIdx.x * 256 + threadIdx.x;
    int node = gt >> 6;
    int lane = threadIdx.x & 63;
    if (node >= n) return;

    float sn = dis[node];                   // self weight (table already carries one dis)
    float2 x0 = __half22float2(Xh[(size_t)node * 64 + lane]);
    float a0x = sn * x0.x, a0y = sn * x0.y;
    float a1x = 0.f, a1y = 0.f;
    float a2x = 0.f, a2y = 0.f;
    float a3x = 0.f, a3y = 0.f;

    const int2 o2 = off2[node];
    const int cnt = o2.y - o2.x;
    const int2* el = ep + o2.x;
    const int nb = cnt >> 2;
    int done = 0;

    if (nb >= 2) {
        int2 q0, q1, q2, q3;
        int2 p0 = el[0], p1 = el[1], p2 = el[2], p3 = el[3];
        q0 = el[4]; q1 = el[5]; q2 = el[6]; q3 = el[7];
        __half2 xc0 = Xh[(size_t)p0.x * 64 + lane];
        __half2 xc1 = Xh[(size_t)p1.x * 64 + lane];
        __half2 xc2 = Xh[(size_t)p2.x * 64 + lane];
        __half2 xc3 = Xh[(size_t)p3.x * 64 + lane];
        float wc0 = __int_as_float(p0.y), wc1 = __int_as_float(p1.y);
        float wc2 = __int_as_float(p2.y), wc3 = __int_as_float(p3.y);

        int b;
        #pragma unroll 2
        for (b = 0; b + 2 < nb; ++b) {
            __half2 xn0 = Xh[(size_t)q0.x * 64 + lane];
            __half2 xn1 = Xh[(size_t)q1.x * 64 + lane];
            __half2 xn2 = Xh[(size_t)q2.x * 64 + lane];
            __half2 xn3 = Xh[(size_t)q3.x * 64 + lane];
            float wn0 = __int_as_float(q0.y), wn1 = __int_as_float(q1.y);
            float wn2 = __int_as_float(q2.y), wn3 = __int_as_float(q3.y);
            const int2* eb = el + (size_t)(b + 2) * 4;
            q0 = eb[0]; q1 = eb[1]; q2 = eb[2]; q3 = eb[3];
            float2 f0 = __half22float2(xc0), f1 = __half22float2(xc1);
            float2 f2 = __half22float2(xc2), f3 = __half22float2(xc3);
            a0x += wc0 * f0.x; a0y += wc0 * f0.y;
            a1x += wc1 * f1.x; a1y += wc1 * f1.y;
            a2x += wc2 * f2.x; a2y += wc2 * f2.y;
            a3x += wc3 * f3.x; a3y += wc3 * f3.y;
            xc0 = xn0; xc1 = xn1; xc2 = xn2; xc3 = xn3;
            wc0 = wn0; wc1 = wn1; wc2 = wn2; wc3 = wn3;
        }
        __half2 xn0 = Xh[(size_t)q0.x * 64 + lane];
        __half2 xn1 = Xh[(size_t)q1.x * 64 + lane];
        __half2 xn2 = Xh[(size_t)q2.x * 64 + lane];
        __half2 xn3 = Xh[(size_t)q3.x * 64 + lane];
        float wn0 = __int_as_float(q0.y), wn1 = __int_as_float(q1.y);
        float wn2 = __int_as_float(q2.y), wn3 = __int_as_float(q3.y);
        {
            float2 f0 = __half22float2(xc0), f1 = __half22float2(xc1);
            float2 f2 = __half22float2(xc2), f3 = __half22float2(xc3);
            a0x += wc0 * f0.x; a0y += wc0 * f0.y;
            a1x += wc1 * f1.x; a1y += wc1 * f1.y;
            a2x += wc2 * f2.x; a2y += wc2 * f2.y;
            a3x += wc3 * f3.x; a3y += wc3 * f3.y;
        }
        {
            float2 f0 = __half22float2(xn0), f1 = __half22float2(xn1);
            float2 f2 = __half22float2(xn2), f3 = __half22float2(xn3);
            a0x += wn0 * f0.x; a0y += wn0 * f0.y;
            a1x += wn1 * f1.x; a1y += wn1 * f1.y;
            a2x += wn2 * f2.x; a2y += wn2 * f2.y;
            a3x += wn3 * f3.x; a3y += wn3 * f3.y;
        }
        done = nb * 4;
    }
    for (int e = done; e < cnt; ++e) {
        int2 p = el[e];
        float2 xv = __half22float2(Xh[(size_t)p.x * 64 + lane]);
        float w = __int_as_float(p.y);
        a0x += w * xv.x; a0y += w * xv.y;
    }
    float rx = (a0x + a1x) + (a2x + a3x);
    float ry = (a0y + a1y) + (a2y + a3y);
    Yh[(size_t)node * 64 + lane] = __floats2half2_rn(rx, ry);
}

// ---------------- SpMM64 (stage C): 4 edges per wave-step (round-11 proven) ----------------
__global__ __launch_bounds__(256) void k_spmm64(const __half* __restrict__ Zh,
                                                const int2* __restrict__ ep,
                                                const int2* __restrict__ off2,
                                                const float* __restrict__ dis,
                                                const float* __restrict__ b6,
                                                float* __restrict__ out, int n)
{
    int gt = blockIdx.x * 256 + threadIdx.x;
    int node = gt >> 6;
    int lane = threadIdx.x & 63;
    if (node >= n) return;
    const int grp = lane >> 4;
    const int l15 = lane & 15;
    const char* Zb = (const char*)Zh;
    const unsigned loff = (unsigned)l15 << 3;    // 8B per lane

    f32x4 acc0 = {0.f, 0.f, 0.f, 0.f};
    f32x4 acc1 = {0.f, 0.f, 0.f, 0.f};

    if (grp == 0) {                              // self-loop term
        float sn = dis[node];
        float2 raw = *(const float2*)(Zb + (((unsigned)node << 7) + loff));
        float2 f0 = __half22float2(((const __half2*)&raw)[0]);
        float2 f1 = __half22float2(((const __half2*)&raw)[1]);
        acc0[0] = sn * f0.x; acc0[1] = sn * f0.y;
        acc0[2] = sn * f1.x; acc0[3] = sn * f1.y;
    }

    const int2 o2 = off2[node];
    const int cnt = o2.y - o2.x;
    const int2* el = ep + o2.x;
    const int nb = cnt >> 2;                     // batches of 4 edges
    int done = 0;

    if (nb >= 2) {
        int2 ec = el[grp];
        float2 xc = *(const float2*)(Zb + (((unsigned)ec.x << 7) + loff));
        int2 en = el[4 + grp];
        float2 xn;

        #pragma unroll 2
        for (int b = 0; b + 2 < nb; ++b) {
            xn = *(const float2*)(Zb + (((unsigned)en.x << 7) + loff));
            int2 e2 = el[(b + 2) * 4 + grp];
            float w = __int_as_float(ec.y);
            float2 f0 = __half22float2(((const __half2*)&xc)[0]);
            float2 f1 = __half22float2(((const __half2*)&xc)[1]);
            if (b & 1) {
                acc1[0] += w * f0.x; acc1[1] += w * f0.y;
                acc1[2] += w * f1.x; acc1[3] += w * f1.y;
            } else {
                acc0[0] += w * f0.x; acc0[1] += w * f0.y;
                acc0[2] += w * f1.x; acc0[3] += w * f1.y;
            }
            ec = en; xc = xn; en = e2;
        }
        // epilogue: batch nb-2 (ec/xc ready) then nb-1 (en, gather now)
        xn = *(const float2*)(Zb + (((unsigned)en.x << 7) + loff));
        {
            float w = __int_as_float(ec.y);
            float2 f0 = __half22float2(((const __half2*)&xc)[0]);
            float2 f1 = __half22float2(((const __half2*)&xc)[1]);
            acc0[0] += w * f0.x; acc0[1] += w * f0.y;
            acc0[2] += w * f1.x; acc0[3] += w * f1.y;
        }
        {
            float w = __int_as_float(en.y);
            float2 f0 = __half22float2(((const __half2*)&xn)[0]);
            float2 f1 = __half22float2(((const __half2*)&xn)[1]);
            acc1[0] += w * f0.x; acc1[1] += w * f0.y;
            acc1[2] += w * f1.x; acc1[3] += w * f1.y;
        }
        done = nb * 4;
    }
    // tail: 0..3 leftover edges, group-parallel with clamp
    for (int e = done; e < cnt; e += 4) {
        int idx = e + grp;
        int2 pe = el[min(idx, cnt - 1)];
        float w = (idx < cnt) ? __int_as_float(pe.y) : 0.f;
        float2 raw = *(const float2*)(Zb + (((unsigned)pe.x << 7) + loff));
        float2 f0 = __half22float2(((const __half2*)&raw)[0]);
        float2 f1 = __half22float2(((const __half2*)&raw)[1]);
        acc0[0] += w * f0.x; acc0[1] += w * f0.y;
        acc0[2] += w * f1.x; acc0[3] += w * f1.y;
    }

    f32x4 r;
    #pragma unroll
    for (int j = 0; j < 4; ++j) {
        r[j] = acc0[j] + acc1[j];
        r[j] += __shfl_xor(r[j], 16);
        r[j] += __shfl_xor(r[j], 32);
    }
    if (lane < 16) {
        float4 bb = *(const float4*)(b6 + 4 * l15);
        float4 o;
        o.x = tanhf(fmaf(r[0], ZSCALE_COMP, bb.x));
        o.y = tanhf(fmaf(r[1], ZSCALE_COMP, bb.y));
        o.z = tanhf(fmaf(r[2], ZSCALE_COMP, bb.z));
        o.w = tanhf(fmaf(r[3], ZSCALE_COMP, bb.w));
        *(float4*)((char*)out + (((size_t)node << 8) + ((unsigned)l15 << 4))) = o;
    }
}

// fast tanh: 1 - 2/(e^{2x}+1) via v_exp + v_rcp
__device__ __forceinline__ float fast_tanh(float x) {
    float e = __expf(2.0f * x);
    return 1.0f - 2.0f * __builtin_amdgcn_rcpf(e + 1.0f);
}

// ---------------- MFMA GEMM, register-resident B (round-8 proven) ----------------
template <int FOUT, int NW, bool ACT>
__global__ __launch_bounds__(256, 2) void k_mgemm(const __half* __restrict__ Yh,
                                                  float IS, float OS,
                                                  const float* __restrict__ dis,
                                                  const __half* __restrict__ Wt0, const float* __restrict__ B0,
                                                  const __half* __restrict__ Wt1, const float* __restrict__ B1,
                                                  const __half* __restrict__ Wt2, const float* __restrict__ B2,
                                                  __half* __restrict__ Out, int nRows)
{
    constexpr int NF = FOUT / 16;
    constexpr int FPW = NF / 4;
    int tid = threadIdx.x;
    int wv = tid >> 6;
    int lane = tid & 63;
    int lo = lane & 15, hi = lane >> 4;
    int r0 = blockIdx.x * 64;

    const __half* Wts[3] = {Wt0, Wt1, Wt2};
    const float*  Bs[3]  = {B0, B1, B2};

    f16x8 bfr[FPW][NW][4];
    float bias[FPW][NW];
    #pragma unroll
    for (int fp = 0; fp < FPW; ++fp) {
        int f = wv * FPW + fp;
        #pragma unroll
        for (int w = 0; w < NW; ++w) {
            const __half* Bp = Wts[w] + (size_t)(f * 16 + lo) * 128 + hi * 8;
            #pragma unroll
            for (int ks = 0; ks < 4; ++ks)
                bfr[fp][w][ks] = *(const f16x8*)(Bp + ks * 32);
            if constexpr (ACT) bias[fp][w] = Bs[w][f * 16 + lo];
        }
    }

    float disr[4][4];
    if constexpr (ACT) {
        #pragma unroll
        for (int rt = 0; rt < 4; ++rt)
            #pragma unroll
            for (int r = 0; r < 4; ++r) {
                int row = r0 + rt * 16 + hi * 4 + r;
                if (row >= nRows) row = nRows - 1;
                disr[rt][r] = dis[row];
            }
    }

    f16x8 a[4], an[4];
    {
        int row = r0 + lo;
        if (row >= nRows) row = nRows - 1;
        const __half* Ap = Yh + (size_t)row * 128 + hi * 8;
        #pragma unroll
        for (int ks = 0; ks < 4; ++ks) a[ks] = *(const f16x8*)(Ap + ks * 32);
    }

    #pragma unroll
    for (int rt = 0; rt < 4; ++rt) {
        if (rt < 3) {
            int row = r0 + (rt + 1) * 16 + lo;
            if (row >= nRows) row = nRows - 1;
            const __half* Ap = Yh + (size_t)row * 128 + hi * 8;
            #pragma unroll
            for (int ks = 0; ks < 4; ++ks) an[ks] = *(const f16x8*)(Ap + ks * 32);
        }
        #pragma unroll
        for (int fp = 0; fp < FPW; ++fp) {
            f32x4 ac0 = {0.f, 0.f, 0.f, 0.f};
            f32x4 ac1 = {0.f, 0.f, 0.f, 0.f};
            f32x4 ac2 = {0.f, 0.f, 0.f, 0.f};
            #pragma unroll
            for (int ks = 0; ks < 4; ++ks) {
                ac0 = __builtin_amdgcn_mfma_f32_16x16x32_f16(a[ks], bfr[fp][0][ks], ac0, 0, 0, 0);
                if constexpr (NW > 1)
                    ac1 = __builtin_amdgcn_mfma_f32_16x16x32_f16(a[ks], bfr[fp][1][ks], ac1, 0, 0, 0);
                if constexpr (NW > 2)
                    ac2 = __builtin_amdgcn_mfma_f32_16x16x32_f16(a[ks], bfr[fp][2][ks], ac2, 0, 0, 0);
            }
            int c = (wv * FPW + fp) * 16 + lo;
            #pragma unroll
            for (int r = 0; r < 4; ++r) {
                int row = r0 + rt * 16 + hi * 4 + r;
                float v;
                if constexpr (ACT) {
                    v = fast_tanh(fmaf(ac0[r], IS, bias[fp][0]));
                    if constexpr (NW > 1) v *= fast_tanh(fmaf(ac1[r], IS, bias[fp][1]));
                    if constexpr (NW > 2) v *= fast_tanh(fmaf(ac2[r], IS, bias[fp][2]));
                    v *= OS * disr[rt][r];
                } else {
                    v = ac0[r] * OS;
                }
                if (row < nRows)
                    Out[(size_t)row * FOUT + c] = __float2half(v);
            }
        }
        #pragma unroll
        for (int ks = 0; ks < 4; ++ks) a[ks] = an[ks];
    }
}

extern "C" void kernel_launch(void* const* d_in, const int* in_sizes, int n_in,
                              void* d_out, int out_size, void* d_ws, size_t ws_size,
                              hipStream_t stream)
{
    const float* h0 = (const float*)d_in[0];
    const int*   ei = (const int*)d_in[1];
    const float* ew = (const float*)d_in[2];
    const float* W1 = (const float*)d_in[3];  const float* b1 = (const float*)d_in[4];
    const float* W2 = (const float*)d_in[5];  const float* b2 = (const float*)d_in[6];
    const float* W3 = (const float*)d_in[7];  const float* b3 = (const float*)d_in[8];
    const float* W4 = (const float*)d_in[9];  const float* b4 = (const float*)d_in[10];
    const float* W5 = (const float*)d_in[11]; const float* b5 = (const float*)d_in[12];
    const float* W6 = (const float*)d_in[13]; const float* b6 = (const float*)d_in[14];

    const int N = in_sizes[0] / FDIM;
    const int E = in_sizes[2];
    const int* rowp = ei;
    const int* colp = ei + E;

    const int NB1 = (E + CHUNK - 1) / CHUNK;
    const int cap1 = E / 40;        // 80000 for E=3.2M (mean 65.5K)
    const int cap2 = E / 2000;      // 1600 for E=3.2M (mean 1024); <= 2048 reg capacity

    char* p = (char*)d_ws;
    auto alloc = [&](size_t bytes) -> void* {
        void* r = (void*)p;
        p += (bytes + 255) & ~(size_t)255;
        return r;
    };
    int* cur1  = (int*)alloc((size_t)B1 * 4);
    int* cur2  = (int*)alloc((size_t)NGRP * 4);
    int* gtot  = (int*)alloc(256);
    int2* off2 = (int2*)alloc((size_t)N * 8);
    float* dis = (float*)alloc((size_t)N * 4);
    ull* rec1  = (ull*)alloc((size_t)B1 * cap1 * 8);    // later aliased by ep
    ull* rec2  = (ull*)alloc((size_t)NGRP * cap2 * 8);  // later aliased by Yh
    __half2* Xh = (__half2*)alloc((size_t)N * FDIM * 2);  // later aliased by Zh
    __half2* Hh = (__half2*)alloc((size_t)N * FDIM * 2);
    __half* W1t = (__half*)alloc((size_t)128 * 128 * 2);
    __half* W2t = (__half*)alloc((size_t)128 * 128 * 2);
    __half* W3t = (__half*)alloc((size_t)128 * 128 * 2);
    __half* W4t = (__half*)alloc((size_t)128 * 128 * 2);
    __half* W5t = (__half*)alloc((size_t)128 * 128 * 2);
    __half* W6t = (__half*)alloc((size_t)64 * 128 * 2);

    int2*    ep = (int2*)rec1;       // rec1 dead after k_p2part
    __half2* Yh = (__half2*)rec2;    // rec2 dead after k_p3
    __half*  Zh = (__half*)Xh;       // Xh dead after stage-A spmm

    // ---- build: 4 kernels, no E-sized scans, no memset ----
    k_init<<<(NGRP + 255) / 256, 256, 0, stream>>>(cur1, cur2, gtot, cap1, cap2);
    k_p1part<<<NB1, 256, 0, stream>>>(colp, rowp, ew, cur1, rec1, E);
    k_p2part<<<B1 * MAXC2, 256, 0, stream>>>(rec1, cur1, cur2, rec2, cap1);
    k_p3<<<NGRP, 256, 0, stream>>>(rec2, cur2, gtot, ep, off2, dis, cap2, N);

    // ---- fused dense prep (cvt + all weight transposes) ----
    const int cvtBlocks = (N * 32 + 255) / 256;
    k_prep<<<cvtBlocks + 352, 256, 0, stream>>>((const float4*)h0, dis, Xh, N * 32,
        W1, W2, W3, W4, W5, W6, W1t, W2t, W3t, W4t, W5t, W6t, cvtBlocks);

    const int sb = (N + 3) / 4;     // 4 waves (nodes) per 256-thread block
    const int gb = (N + 63) / 64;   // 64-row tiles

    // Stage A: Yh = agg(Xh) ; Hh = HSCALE*dis*tanh(YhW1+b1)*tanh(YhW2+b2)*tanh(YhW3+b3)
    k_spmm<<<sb, 256, 0, stream>>>(Xh, ep, off2, dis, Yh, N);
    k_mgemm<128, 3, true><<<gb, 256, 0, stream>>>((const __half*)Yh, 1.0f, HSCALE, dis,
        W1t, b1, W2t, b2, W3t, b3, (__half*)Hh, N);
    // Stage B: Yh = agg(Hh) ; Hh = HSCALE*dis*tanh(2^-14 YhW4+b4)*tanh(2^-14 YhW5+b5)
    k_spmm<<<sb, 256, 0, stream>>>(Hh, ep, off2, dis, Yh, N);
    k_mgemm<128, 2, true><<<gb, 256, 0, stream>>>((const __half*)Yh, HSCALE_INV, HSCALE, dis,
        W4t, b4, W5t, b5, nullptr, nullptr, (__half*)Hh, N);
    // Stage C: project first (Zh = ZSCALE * Hh W6, 64 features), then aggregate+tanh -> out
    k_mgemm<64, 1, false><<<gb, 256, 0, stream>>>((const __half*)Hh, 1.0f, ZSCALE, nullptr,
        W6t, b6, nullptr, nullptr, nullptr, nullptr, Zh, N);
    k_spmm64<<<sb, 256, 0, stream>>>(Zh, ep, off2, dis, b6, (float*)d_out, N);
}

// Round 13
// 471.959 us; speedup vs baseline: 1.0793x; 1.0793x over previous
//
#include <hip/hip_runtime.h>
#include <hip/hip_bf16.h>
#include <hip/hip_fp16.h>

constexpr int FDIM = 128;
#define HSCALE 16384.0f         // 2^14: |h|<1 -> scaled <16384 <= 65504, always safe
#define HSCALE_INV (1.0f/16384.0f)
#define ZSCALE 0.125f           // extra headroom for Zh = Hh @ W6
#define ZSCALE_COMP (HSCALE_INV * 8.0f)

typedef _Float16 f16x8 __attribute__((ext_vector_type(8)));
typedef float f32x4 __attribute__((ext_vector_type(4)));
typedef unsigned long long ull;

// ===================== atomic-reserved CSR build (2 partition passes) =====================
// record: [col:17 @47][row:17 @30][ew_f16 @0]
constexpr int CHUNK = 4096;
constexpr int B1 = 64;
constexpr int B2 = 64;
constexpr int NGRP = B1 * B2;   // 4096
constexpr int MAXC2 = 20;

__global__ __launch_bounds__(256) void k_init(int* __restrict__ cur1,
                                              int* __restrict__ cur2,
                                              int cap1, int cap2)
{
    int i = blockIdx.x * 256 + threadIdx.x;
    if (i < B1) cur1[i] = i * cap1;
    if (i < NGRP) cur2[i] = i * cap2;
}

// pass 1: chunk -> 64 coarse buckets.
__global__ __launch_bounds__(256) void k_p1part(const int* __restrict__ col,
                                                const int* __restrict__ row,
                                                const float* __restrict__ ew,
                                                int* __restrict__ cur1,
                                                ull* __restrict__ rec1, int E)
{
    __shared__ ull stage[CHUNK];
    __shared__ int hcnt[B1], lb[B1], gb[B1], lcur[B1];
    int blk = blockIdx.x, t = threadIdx.x;
    if (t < B1) hcnt[t] = 0;
    __syncthreads();
    int base = blk * CHUNK;
    ull rc[16];
    #pragma unroll
    for (int it = 0; it < 16; ++it) {
        int g = base + it * 256 + t;
        if (g < E) {
            int c = col[g], r = row[g];
            rc[it] = ((ull)c << 47) | ((ull)r << 30) |
                     (ull)__half_as_ushort(__float2half(ew[g]));
            atomicAdd(&hcnt[c >> 11], 1);
        } else rc[it] = ~0ull;
    }
    __syncthreads();
    if (t == 0) {
        int run = 0;
        for (int b = 0; b < B1; ++b) { lb[b] = run; run += hcnt[b]; }
    }
    __syncthreads();
    if (t < B1) { lcur[t] = lb[t]; gb[t] = atomicAdd(&cur1[t], hcnt[t]); }
    __syncthreads();
    #pragma unroll
    for (int it = 0; it < 16; ++it) {
        if (rc[it] != ~0ull) {
            int b = (int)(rc[it] >> 58);
            stage[atomicAdd(&lcur[b], 1)] = rc[it];
        }
    }
    __syncthreads();
    int here = min(CHUNK, E - base);
    for (int j = t; j < here; j += 256) {
        ull v = stage[j];
        int b = (int)(v >> 58);
        rec1[gb[b] + (j - lb[b])] = v;
    }
}

// pass 2: within each coarse bucket, partition chunks into 64 sub-buckets (groups).
__global__ __launch_bounds__(256) void k_p2part(const ull* __restrict__ rec1,
                                                const int* __restrict__ cur1,
                                                int* __restrict__ cur2,
                                                ull* __restrict__ rec2,
                                                int cap1)
{
    __shared__ ull stage[CHUNK];
    __shared__ int hcnt[B2], lb[B2], gb[B2], lcur[B2];
    int b = blockIdx.x / MAXC2, ci = blockIdx.x % MAXC2, t = threadIdx.x;
    int S1 = b * cap1;
    int size = cur1[b] - S1;
    for (int c = ci; c * CHUNK < size; c += MAXC2) {
        int cb = S1 + c * CHUNK;
        int m = min(CHUNK, size - c * CHUNK);
        __syncthreads();
        if (t < B2) hcnt[t] = 0;
        __syncthreads();
        ull rc[16];
        #pragma unroll
        for (int it = 0; it < 16; ++it) {
            int j = it * 256 + t;
            if (j < m) {
                ull v = rec1[cb + j];
                rc[it] = v;
                atomicAdd(&hcnt[(int)((v >> 52) & 63)], 1);
            } else rc[it] = ~0ull;
        }
        __syncthreads();
        if (t == 0) {
            int run = 0;
            for (int s = 0; s < B2; ++s) { lb[s] = run; run += hcnt[s]; }
        }
        __syncthreads();
        if (t < B2) { lcur[t] = lb[t]; gb[t] = atomicAdd(&cur2[b * B2 + t], hcnt[t]); }
        __syncthreads();
        #pragma unroll
        for (int it = 0; it < 16; ++it) {
            if (rc[it] != ~0ull) {
                int s = (int)((rc[it] >> 52) & 63);
                stage[atomicAdd(&lcur[s], 1)] = rc[it];
            }
        }
        __syncthreads();
        for (int j = t; j < m; j += 256) {
            ull v = stage[j];
            int s = (int)((v >> 52) & 63);
            rec2[gb[s] + (j - lb[s])] = v;
        }
    }
}

// one-block exclusive scan of the 4096 group sizes -> compact output bases
__global__ __launch_bounds__(1024) void k_gscan(const int* __restrict__ cur2,
                                                int* __restrict__ gbase, int cap2)
{
    __shared__ int s[1024];
    __shared__ int carry;
    int t = threadIdx.x;
    if (t == 0) carry = 0;
    __syncthreads();
    for (int tile = 0; tile < 4; ++tile) {
        int g = tile * 1024 + t;
        int v = cur2[g] - g * cap2;
        s[t] = v;
        __syncthreads();
        for (int o = 1; o < 1024; o <<= 1) {
            int u = (t >= o) ? s[t - o] : 0;
            __syncthreads();
            s[t] += u;
            __syncthreads();
        }
        gbase[g] = carry + s[t] - v;    // exclusive
        __syncthreads();
        if (t == 1023) carry += s[t];
        __syncthreads();
    }
}

// final: counting sort per 32-node group; emits compact ep=(row, ew*dis[col]), off, dis
__global__ __launch_bounds__(256) void k_p3(const ull* __restrict__ rec2,
                                            const int* __restrict__ cur2,
                                            const int* __restrict__ gbase,
                                            int2* __restrict__ ep, int* __restrict__ off,
                                            float* __restrict__ dis, int cap2, int N, int E)
{
    __shared__ int h[32], lb[32], cur[32];
    __shared__ float dg[32], sdis[32];
    int g = blockIdx.x, t = threadIdx.x;
    int S1 = g * cap2;
    int S2 = cur2[g];
    int base = gbase[g];
    if (t < 32) { h[t] = 0; dg[t] = 0.f; }
    __syncthreads();
    for (int i = S1 + t; i < S2; i += 256) {
        ull rc = rec2[i];
        int nl = (int)((rc >> 47) & 31);
        atomicAdd(&h[nl], 1);
        atomicAdd(&dg[nl], __half2float(__ushort_as_half((unsigned short)(rc & 0xFFFF))));
    }
    __syncthreads();
    if (t == 0) {
        int run = base;
        for (int k = 0; k < 32; ++k) { lb[k] = run; run += h[k]; }
    }
    __syncthreads();
    if (t < 32) {
        cur[t] = lb[t];
        sdis[t] = 1.0f / sqrtf(dg[t] + 1.0f);   // self-loop included; >= 1 always
        int node = g * 32 + t;
        if (node < N) { off[node] = lb[t]; dis[node] = sdis[t]; }
    }
    if (g == 0 && t == 0) off[N] = E;
    __syncthreads();
    for (int i = S1 + t; i < S2; i += 256) {
        ull rc = rec2[i];
        int nl = (int)((rc >> 47) & 31);
        int p = atomicAdd(&cur[nl], 1);
        float w = __half2float(__ushort_as_half((unsigned short)(rc & 0xFFFF))) * sdis[nl];
        ep[p] = make_int2((int)((rc >> 30) & 0x1FFFF), __float_as_int(w));
    }
}

// ---------------- fused prep: h0 f32->f16 with dis pre-scale  +  6 W transposes ----------------
__global__ __launch_bounds__(256) void k_prep(const float4* __restrict__ in,
                                              const float* __restrict__ dis, __half2* __restrict__ out, int n4,
                                              const float* __restrict__ W1, const float* __restrict__ W2,
                                              const float* __restrict__ W3, const float* __restrict__ W4,
                                              const float* __restrict__ W5, const float* __restrict__ W6,
                                              __half* __restrict__ T1, __half* __restrict__ T2,
                                              __half* __restrict__ T3, __half* __restrict__ T4,
                                              __half* __restrict__ T5, __half* __restrict__ T6,
                                              int cvtBlocks)
{
    if ((int)blockIdx.x < cvtBlocks) {
        int i = blockIdx.x * 256 + threadIdx.x;
        if (i >= n4) return;
        float4 v = in[i];
        float d = dis[i >> 5];          // 32 float4 per row
        __half2 a = __floats2half2_rn(v.x * d, v.y * d);
        __half2 b = __floats2half2_rn(v.z * d, v.w * d);
        float2 pk;
        ((__half2*)&pk)[0] = a;
        ((__half2*)&pk)[1] = b;
        *(float2*)&out[(size_t)i * 2] = pk;
    } else {
        int idx = (blockIdx.x - cvtBlocks) * 256 + threadIdx.x;
        const float* W; __half* T; int local, nf;
        if (idx < 81920) {
            int seg = idx >> 14;
            local = idx & 16383;
            nf = 128;
            const float* Ws[5] = {W1, W2, W3, W4, W5};
            __half* Ts[5] = {T1, T2, T3, T4, T5};
            W = Ws[seg]; T = Ts[seg];
        } else if (idx < 90112) {
            local = idx - 81920;
            nf = 64;
            W = W6; T = T6;
        } else return;
        int n = local >> 7, k = local & 127;
        T[local] = __float2half(W[(size_t)k * nf + n]);
    }
}

// ---------------- SpMM: Yh = fp16(aggregate), round-8 proven (4-wide, 2-deep) ----------------
__global__ __launch_bounds__(256) void k_spmm(const __half2* __restrict__ Xh,
                                              const int2* __restrict__ ep,
                                              const int* __restrict__ off,
                                              const float* __restrict__ dis,
                                              __half2* __restrict__ Yh, int n)
{
    int gt = blockIdx.x * 256 + threadIdx.x;
    int node = gt >> 6;
    int lane = threadIdx.x & 63;
    if (node >= n) return;

    float sn = dis[node];                   // self weight (table already carries one dis)
    float2 x0 = __half22float2(Xh[(size_t)node * 64 + lane]);
    float a0x = sn * x0.x, a0y = sn * x0.y;
    float a1x = 0.f, a1y = 0.f;
    float a2x = 0.f, a2y = 0.f;
    float a3x = 0.f, a3y = 0.f;

    const int e0 = off[node];
    const int cnt = off[node + 1] - e0;
    const int2* el = ep + e0;
    const int nb = cnt >> 2;
    int done = 0;

    if (nb >= 2) {
        int2 q0, q1, q2, q3;
        int2 p0 = el[0], p1 = el[1], p2 = el[2], p3 = el[3];
        q0 = el[4]; q1 = el[5]; q2 = el[6]; q3 = el[7];
        __half2 xc0 = Xh[(size_t)p0.x * 64 + lane];
        __half2 xc1 = Xh[(size_t)p1.x * 64 + lane];
        __half2 xc2 = Xh[(size_t)p2.x * 64 + lane];
        __half2 xc3 = Xh[(size_t)p3.x * 64 + lane];
        float wc0 = __int_as_float(p0.y), wc1 = __int_as_float(p1.y);
        float wc2 = __int_as_float(p2.y), wc3 = __int_as_float(p3.y);

        int b;
        #pragma unroll 2
        for (b = 0; b + 2 < nb; ++b) {
            __half2 xn0 = Xh[(size_t)q0.x * 64 + lane];
            __half2 xn1 = Xh[(size_t)q1.x * 64 + lane];
            __half2 xn2 = Xh[(size_t)q2.x * 64 + lane];
            __half2 xn3 = Xh[(size_t)q3.x * 64 + lane];
            float wn0 = __int_as_float(q0.y), wn1 = __int_as_float(q1.y);
            float wn2 = __int_as_float(q2.y), wn3 = __int_as_float(q3.y);
            const int2* eb = el + (size_t)(b + 2) * 4;
            q0 = eb[0]; q1 = eb[1]; q2 = eb[2]; q3 = eb[3];
            float2 f0 = __half22float2(xc0), f1 = __half22float2(xc1);
            float2 f2 = __half22float2(xc2), f3 = __half22float2(xc3);
            a0x += wc0 * f0.x; a0y += wc0 * f0.y;
            a1x += wc1 * f1.x; a1y += wc1 * f1.y;
            a2x += wc2 * f2.x; a2y += wc2 * f2.y;
            a3x += wc3 * f3.x; a3y += wc3 * f3.y;
            xc0 = xn0; xc1 = xn1; xc2 = xn2; xc3 = xn3;
            wc0 = wn0; wc1 = wn1; wc2 = wn2; wc3 = wn3;
        }
        __half2 xn0 = Xh[(size_t)q0.x * 64 + lane];
        __half2 xn1 = Xh[(size_t)q1.x * 64 + lane];
        __half2 xn2 = Xh[(size_t)q2.x * 64 + lane];
        __half2 xn3 = Xh[(size_t)q3.x * 64 + lane];
        float wn0 = __int_as_float(q0.y), wn1 = __int_as_float(q1.y);
        float wn2 = __int_as_float(q2.y), wn3 = __int_as_float(q3.y);
        {
            float2 f0 = __half22float2(xc0), f1 = __half22float2(xc1);
            float2 f2 = __half22float2(xc2), f3 = __half22float2(xc3);
            a0x += wc0 * f0.x; a0y += wc0 * f0.y;
            a1x += wc1 * f1.x; a1y += wc1 * f1.y;
            a2x += wc2 * f2.x; a2y += wc2 * f2.y;
            a3x += wc3 * f3.x; a3y += wc3 * f3.y;
        }
        {
            float2 f0 = __half22float2(xn0), f1 = __half22float2(xn1);
            float2 f2 = __half22float2(xn2), f3 = __half22float2(xn3);
            a0x += wn0 * f0.x; a0y += wn0 * f0.y;
            a1x += wn1 * f1.x; a1y += wn1 * f1.y;
            a2x += wn2 * f2.x; a2y += wn2 * f2.y;
            a3x += wn3 * f3.x; a3y += wn3 * f3.y;
        }
        done = nb * 4;
    }
    for (int e = done; e < cnt; ++e) {
        int2 p = el[e];
        float2 xv = __half22float2(Xh[(size_t)p.x * 64 + lane]);
        float w = __int_as_float(p.y);
        a0x += w * xv.x; a0y += w * xv.y;
    }
    float rx = (a0x + a1x) + (a2x + a3x);
    float ry = (a0y + a1y) + (a2y + a3y);
    Yh[(size_t)node * 64 + lane] = __floats2half2_rn(rx, ry);
}

// ---------------- SpMM64 (stage C): 4 edges per wave-step (round-11 proven) ----------------
__global__ __launch_bounds__(256) void k_spmm64(const __half* __restrict__ Zh,
                                                const int2* __restrict__ ep,
                                                const int* __restrict__ off,
                                                const float* __restrict__ dis,
                                                const float* __restrict__ b6,
                                                float* __restrict__ out, int n)
{
    int gt = blockIdx.x * 256 + threadIdx.x;
    int node = gt >> 6;
    int lane = threadIdx.x & 63;
    if (node >= n) return;
    const int grp = lane >> 4;
    const int l15 = lane & 15;
    const char* Zb = (const char*)Zh;
    const unsigned loff = (unsigned)l15 << 3;    // 8B per lane

    f32x4 acc0 = {0.f, 0.f, 0.f, 0.f};
    f32x4 acc1 = {0.f, 0.f, 0.f, 0.f};

    if (grp == 0) {                              // self-loop term
        float sn = dis[node];
        float2 raw = *(const float2*)(Zb + (((unsigned)node << 7) + loff));
        float2 f0 = __half22float2(((const __half2*)&raw)[0]);
        float2 f1 = __half22float2(((const __half2*)&raw)[1]);
        acc0[0] = sn * f0.x; acc0[1] = sn * f0.y;
        acc0[2] = sn * f1.x; acc0[3] = sn * f1.y;
    }

    const int e0 = off[node];
    const int cnt = off[node + 1] - e0;
    const int2* el = ep + e0;
    const int nb = cnt >> 2;                     // batches of 4 edges
    int done = 0;

    if (nb >= 2) {
        int2 ec = el[grp];
        float2 xc = *(const float2*)(Zb + (((unsigned)ec.x << 7) + loff));
        int2 en = el[4 + grp];
        float2 xn;

        #pragma unroll 2
        for (int b = 0; b + 2 < nb; ++b) {
            xn = *(const float2*)(Zb + (((unsigned)en.x << 7) + loff));
            int2 e2 = el[(b + 2) * 4 + grp];
            float w = __int_as_float(ec.y);
            float2 f0 = __half22float2(((const __half2*)&xc)[0]);
            float2 f1 = __half22float2(((const __half2*)&xc)[1]);
            if (b & 1) {
                acc1[0] += w * f0.x; acc1[1] += w * f0.y;
                acc1[2] += w * f1.x; acc1[3] += w * f1.y;
            } else {
                acc0[0] += w * f0.x; acc0[1] += w * f0.y;
                acc0[2] += w * f1.x; acc0[3] += w * f1.y;
            }
            ec = en; xc = xn; en = e2;
        }
        // epilogue: batch nb-2 (ec/xc ready) then nb-1 (en, gather now)
        xn = *(const float2*)(Zb + (((unsigned)en.x << 7) + loff));
        {
            float w = __int_as_float(ec.y);
            float2 f0 = __half22float2(((const __half2*)&xc)[0]);
            float2 f1 = __half22float2(((const __half2*)&xc)[1]);
            acc0[0] += w * f0.x; acc0[1] += w * f0.y;
            acc0[2] += w * f1.x; acc0[3] += w * f1.y;
        }
        {
            float w = __int_as_float(en.y);
            float2 f0 = __half22float2(((const __half2*)&xn)[0]);
            float2 f1 = __half22float2(((const __half2*)&xn)[1]);
            acc1[0] += w * f0.x; acc1[1] += w * f0.y;
            acc1[2] += w * f1.x; acc1[3] += w * f1.y;
        }
        done = nb * 4;
    }
    // tail: 0..3 leftover edges, group-parallel with clamp
    for (int e = done; e < cnt; e += 4) {
        int idx = e + grp;
        int2 pe = el[min(idx, cnt - 1)];
        float w = (idx < cnt) ? __int_as_float(pe.y) : 0.f;
        float2 raw = *(const float2*)(Zb + (((unsigned)pe.x << 7) + loff));
        float2 f0 = __half22float2(((const __half2*)&raw)[0]);
        float2 f1 = __half22float2(((const __half2*)&raw)[1]);
        acc0[0] += w * f0.x; acc0[1] += w * f0.y;
        acc0[2] += w * f1.x; acc0[3] += w * f1.y;
    }

    f32x4 r;
    #pragma unroll
    for (int j = 0; j < 4; ++j) {
        r[j] = acc0[j] + acc1[j];
        r[j] += __shfl_xor(r[j], 16);
        r[j] += __shfl_xor(r[j], 32);
    }
    if (lane < 16) {
        float4 bb = *(const float4*)(b6 + 4 * l15);
        float4 o;
        o.x = tanhf(fmaf(r[0], ZSCALE_COMP, bb.x));
        o.y = tanhf(fmaf(r[1], ZSCALE_COMP, bb.y));
        o.z = tanhf(fmaf(r[2], ZSCALE_COMP, bb.z));
        o.w = tanhf(fmaf(r[3], ZSCALE_COMP, bb.w));
        *(float4*)((char*)out + (((size_t)node << 8) + ((unsigned)l15 << 4))) = o;
    }
}

// fast tanh: 1 - 2/(e^{2x}+1) via v_exp + v_rcp
__device__ __forceinline__ float fast_tanh(float x) {
    float e = __expf(2.0f * x);
    return 1.0f - 2.0f * __builtin_amdgcn_rcpf(e + 1.0f);
}

// ---------------- MFMA GEMM, register-resident B (round-8 proven; stage A only) ----------------
template <int FOUT, int NW, bool ACT>
__global__ __launch_bounds__(256, 2) void k_mgemm(const __half* __restrict__ Yh,
                                                  float IS, float OS,
                                                  const float* __restrict__ dis,
                                                  const __half* __restrict__ Wt0, const float* __restrict__ B0,
                                                  const __half* __restrict__ Wt1, const float* __restrict__ B1,
                                                  const __half* __restrict__ Wt2, const float* __restrict__ B2,
                                                  __half* __restrict__ Out, int nRows)
{
    constexpr int NF = FOUT / 16;
    constexpr int FPW = NF / 4;
    int tid = threadIdx.x;
    int wv = tid >> 6;
    int lane = tid & 63;
    int lo = lane & 15, hi = lane >> 4;
    int r0 = blockIdx.x * 64;

    const __half* Wts[3] = {Wt0, Wt1, Wt2};
    const float*  Bs[3]  = {B0, B1, B2};

    f16x8 bfr[FPW][NW][4];
    float bias[FPW][NW];
    #pragma unroll
    for (int fp = 0; fp < FPW; ++fp) {
        int f = wv * FPW + fp;
        #pragma unroll
        for (int w = 0; w < NW; ++w) {
            const __half* Bp = Wts[w] + (size_t)(f * 16 + lo) * 128 + hi * 8;
            #pragma unroll
            for (int ks = 0; ks < 4; ++ks)
                bfr[fp][w][ks] = *(const f16x8*)(Bp + ks * 32);
            if constexpr (ACT) bias[fp][w] = Bs[w][f * 16 + lo];
        }
    }

    float disr[4][4];
    if constexpr (ACT) {
        #pragma unroll
        for (int rt = 0; rt < 4; ++rt)
            #pragma unroll
            for (int r = 0; r < 4; ++r) {
                int row = r0 + rt * 16 + hi * 4 + r;
                if (row >= nRows) row = nRows - 1;
                disr[rt][r] = dis[row];
            }
    }

    f16x8 a[4], an[4];
    {
        int row = r0 + lo;
        if (row >= nRows) row = nRows - 1;
        const __half* Ap = Yh + (size_t)row * 128 + hi * 8;
        #pragma unroll
        for (int ks = 0; ks < 4; ++ks) a[ks] = *(const f16x8*)(Ap + ks * 32);
    }

    #pragma unroll
    for (int rt = 0; rt < 4; ++rt) {
        if (rt < 3) {
            int row = r0 + (rt + 1) * 16 + lo;
            if (row >= nRows) row = nRows - 1;
            const __half* Ap = Yh + (size_t)row * 128 + hi * 8;
            #pragma unroll
            for (int ks = 0; ks < 4; ++ks) an[ks] = *(const f16x8*)(Ap + ks * 32);
        }
        #pragma unroll
        for (int fp = 0; fp < FPW; ++fp) {
            f32x4 ac0 = {0.f, 0.f, 0.f, 0.f};
            f32x4 ac1 = {0.f, 0.f, 0.f, 0.f};
            f32x4 ac2 = {0.f, 0.f, 0.f, 0.f};
            #pragma unroll
            for (int ks = 0; ks < 4; ++ks) {
                ac0 = __builtin_amdgcn_mfma_f32_16x16x32_f16(a[ks], bfr[fp][0][ks], ac0, 0, 0, 0);
                if constexpr (NW > 1)
                    ac1 = __builtin_amdgcn_mfma_f32_16x16x32_f16(a[ks], bfr[fp][1][ks], ac1, 0, 0, 0);
                if constexpr (NW > 2)
                    ac2 = __builtin_amdgcn_mfma_f32_16x16x32_f16(a[ks], bfr[fp][2][ks], ac2, 0, 0, 0);
            }
            int c = (wv * FPW + fp) * 16 + lo;
            #pragma unroll
            for (int r = 0; r < 4; ++r) {
                int row = r0 + rt * 16 + hi * 4 + r;
                float v;
                if constexpr (ACT) {
                    v = fast_tanh(fmaf(ac0[r], IS, bias[fp][0]));
                    if constexpr (NW > 1) v *= fast_tanh(fmaf(ac1[r], IS, bias[fp][1]));
                    if constexpr (NW > 2) v *= fast_tanh(fmaf(ac2[r], IS, bias[fp][2]));
                    v *= OS * disr[rt][r];
                } else {
                    v = ac0[r] * OS;
                }
                if (row < nRows)
                    Out[(size_t)row * FOUT + c] = __float2half(v);
            }
        }
        #pragma unroll
        for (int ks = 0; ks < 4; ++ks) a[ks] = an[ks];
    }
}

// ---------------- Fused stage B+C: h45 GEMM (NW=2, tanh-product) -> LDS -> @W6 -> Zh ----------------
// Phase 1 identical math to k_mgemm<128,2,true> but writes the fp16 tile to LDS
// (padded stride 136 halves: phase-2 ds_read_b128 lands 2 lanes/bank = free).
// Phase 2: wave wv computes output cols [wv*16, wv*16+16) of Zh = ZSCALE*(tile @ W6t).
__global__ __launch_bounds__(256, 2) void k_mgemmBC(const __half* __restrict__ Yh,
                                                    float IS, float OS,
                                                    const float* __restrict__ dis,
                                                    const __half* __restrict__ Wt0, const float* __restrict__ B0,
                                                    const __half* __restrict__ Wt1, const float* __restrict__ B1,
                                                    const __half* __restrict__ Wt6,
                                                    __half* __restrict__ Zh, int nRows)
{
    constexpr int LDH = 136;
    __shared__ __half tile[64 * LDH];
    int tid = threadIdx.x;
    int wv = tid >> 6;
    int lane = tid & 63;
    int lo = lane & 15, hi = lane >> 4;
    int r0 = blockIdx.x * 64;

    const __half* Wts[2] = {Wt0, Wt1};
    const float*  Bs[2]  = {B0, B1};

    f16x8 bfr[2][2][4];
    float bias[2][2];
    #pragma unroll
    for (int fp = 0; fp < 2; ++fp) {
        int f = wv * 2 + fp;
        #pragma unroll
        for (int w = 0; w < 2; ++w) {
            const __half* Bp = Wts[w] + (size_t)(f * 16 + lo) * 128 + hi * 8;
            #pragma unroll
            for (int ks = 0; ks < 4; ++ks)
                bfr[fp][w][ks] = *(const f16x8*)(Bp + ks * 32);
            bias[fp][w] = Bs[w][f * 16 + lo];
        }
    }

    float disr[4][4];
    #pragma unroll
    for (int rt = 0; rt < 4; ++rt)
        #pragma unroll
        for (int r = 0; r < 4; ++r) {
            int row = r0 + rt * 16 + hi * 4 + r;
            if (row >= nRows) row = nRows - 1;
            disr[rt][r] = dis[row];
        }

    f16x8 a[4], an[4];
    {
        int row = r0 + lo;
        if (row >= nRows) row = nRows - 1;
        const __half* Ap = Yh + (size_t)row * 128 + hi * 8;
        #pragma unroll
        for (int ks = 0; ks < 4; ++ks) a[ks] = *(const f16x8*)(Ap + ks * 32);
    }

    #pragma unroll
    for (int rt = 0; rt < 4; ++rt) {
        if (rt < 3) {
            int row = r0 + (rt + 1) * 16 + lo;
            if (row >= nRows) row = nRows - 1;
            const __half* Ap = Yh + (size_t)row * 128 + hi * 8;
            #pragma unroll
            for (int ks = 0; ks < 4; ++ks) an[ks] = *(const f16x8*)(Ap + ks * 32);
        }
        #pragma unroll
        for (int fp = 0; fp < 2; ++fp) {
            f32x4 ac0 = {0.f, 0.f, 0.f, 0.f};
            f32x4 ac1 = {0.f, 0.f, 0.f, 0.f};
            #pragma unroll
            for (int ks = 0; ks < 4; ++ks) {
                ac0 = __builtin_amdgcn_mfma_f32_16x16x32_f16(a[ks], bfr[fp][0][ks], ac0, 0, 0, 0);
                ac1 = __builtin_amdgcn_mfma_f32_16x16x32_f16(a[ks], bfr[fp][1][ks], ac1, 0, 0, 0);
            }
            int c = (wv * 2 + fp) * 16 + lo;
            #pragma unroll
            for (int r = 0; r < 4; ++r) {
                float v = fast_tanh(fmaf(ac0[r], IS, bias[fp][0]))
                        * fast_tanh(fmaf(ac1[r], IS, bias[fp][1]));
                v *= OS * disr[rt][r];
                tile[(rt * 16 + hi * 4 + r) * LDH + c] = __float2half(v);
            }
        }
        #pragma unroll
        for (int ks = 0; ks < 4; ++ks) a[ks] = an[ks];
    }
    __syncthreads();

    // phase 2: Zh = ZSCALE * tile @ W6t
    f16x8 b6f[4];
    {
        const __half* Bp = Wt6 + (size_t)(wv * 16 + lo) * 128 + hi * 8;
        #pragma unroll
        for (int ks = 0; ks < 4; ++ks) b6f[ks] = *(const f16x8*)(Bp + ks * 32);
    }
    int c2 = wv * 16 + lo;
    #pragma unroll
    for (int rt = 0; rt < 4; ++rt) {
        f16x8 a2[4];
        const __half* Tp = &tile[(rt * 16 + lo) * LDH + hi * 8];
        #pragma unroll
        for (int ks = 0; ks < 4; ++ks) a2[ks] = *(const f16x8*)(Tp + ks * 32);
        f32x4 acc = {0.f, 0.f, 0.f, 0.f};
        #pragma unroll
        for (int ks = 0; ks < 4; ++ks)
            acc = __builtin_amdgcn_mfma_f32_16x16x32_f16(a2[ks], b6f[ks], acc, 0, 0, 0);
        #pragma unroll
        for (int r = 0; r < 4; ++r) {
            int row = r0 + rt * 16 + hi * 4 + r;
            if (row < nRows)
                Zh[(size_t)row * 64 + c2] = __float2half(acc[r] * ZSCALE);
        }
    }
}

extern "C" void kernel_launch(void* const* d_in, const int* in_sizes, int n_in,
                              void* d_out, int out_size, void* d_ws, size_t ws_size,
                              hipStream_t stream)
{
    const float* h0 = (const float*)d_in[0];
    const int*   ei = (const int*)d_in[1];
    const float* ew = (const float*)d_in[2];
    const float* W1 = (const float*)d_in[3];  const float* b1 = (const float*)d_in[4];
    const float* W2 = (const float*)d_in[5];  const float* b2 = (const float*)d_in[6];
    const float* W3 = (const float*)d_in[7];  const float* b3 = (const float*)d_in[8];
    const float* W4 = (const float*)d_in[9];  const float* b4 = (const float*)d_in[10];
    const float* W5 = (const float*)d_in[11]; const float* b5 = (const float*)d_in[12];
    const float* W6 = (const float*)d_in[13]; const float* b6 = (const float*)d_in[14];

    const int N = in_sizes[0] / FDIM;
    const int E = in_sizes[2];
    const int* rowp = ei;
    const int* colp = ei + E;

    const int NB1 = (E + CHUNK - 1) / CHUNK;
    const int cap1 = E / 40;        // 80000 for E=3.2M (mean 65.5K)
    const int cap2 = E / 2000;      // 1600 for E=3.2M (mean 1024)

    char* p = (char*)d_ws;
    auto alloc = [&](size_t bytes) -> void* {
        void* r = (void*)p;
        p += (bytes + 255) & ~(size_t)255;
        return r;
    };
    int* cur1  = (int*)alloc((size_t)B1 * 4);
    int* cur2  = (int*)alloc((size_t)NGRP * 4);
    int* gbase = (int*)alloc((size_t)(NGRP + 1) * 4);
    int* off   = (int*)alloc((size_t)(N + 1) * 4);
    float* dis = (float*)alloc((size_t)N * 4);
    ull* rec1  = (ull*)alloc((size_t)B1 * cap1 * 8);    // later aliased by ep
    ull* rec2  = (ull*)alloc((size_t)NGRP * cap2 * 8);  // later aliased by Yh
    __half2* Xh = (__half2*)alloc((size_t)N * FDIM * 2);  // later aliased by Zh
    __half2* Hh = (__half2*)alloc((size_t)N * FDIM * 2);
    __half* W1t = (__half*)alloc((size_t)128 * 128 * 2);
    __half* W2t = (__half*)alloc((size_t)128 * 128 * 2);
    __half* W3t = (__half*)alloc((size_t)128 * 128 * 2);
    __half* W4t = (__half*)alloc((size_t)128 * 128 * 2);
    __half* W5t = (__half*)alloc((size_t)128 * 128 * 2);
    __half* W6t = (__half*)alloc((size_t)64 * 128 * 2);

    int2*    ep = (int2*)rec1;       // rec1 dead after k_p2part
    __half2* Yh = (__half2*)rec2;    // rec2 dead after k_p3
    __half*  Zh = (__half*)Xh;       // Xh dead after stage-A spmm

    // ---- build (round-11 proven: gscan-based compact bases, no hot atomic) ----
    k_init<<<(NGRP + 255) / 256, 256, 0, stream>>>(cur1, cur2, cap1, cap2);
    k_p1part<<<NB1, 256, 0, stream>>>(colp, rowp, ew, cur1, rec1, E);
    k_p2part<<<B1 * MAXC2, 256, 0, stream>>>(rec1, cur1, cur2, rec2, cap1);
    k_gscan<<<1, 1024, 0, stream>>>(cur2, gbase, cap2);
    k_p3<<<NGRP, 256, 0, stream>>>(rec2, cur2, gbase, ep, off, dis, cap2, N, E);

    // ---- fused dense prep (cvt + all weight transposes) ----
    const int cvtBlocks = (N * 32 + 255) / 256;
    k_prep<<<cvtBlocks + 352, 256, 0, stream>>>((const float4*)h0, dis, Xh, N * 32,
        W1, W2, W3, W4, W5, W6, W1t, W2t, W3t, W4t, W5t, W6t, cvtBlocks);

    const int sb = (N + 3) / 4;     // 4 waves (nodes) per 256-thread block
    const int gb = (N + 63) / 64;   // 64-row tiles

    // Stage A: Yh = agg(Xh) ; Hh = HSCALE*dis*tanh(YhW1+b1)*tanh(YhW2+b2)*tanh(YhW3+b3)
    k_spmm<<<sb, 256, 0, stream>>>(Xh, ep, off, dis, Yh, N);
    k_mgemm<128, 3, true><<<gb, 256, 0, stream>>>((const __half*)Yh, 1.0f, HSCALE, dis,
        W1t, b1, W2t, b2, W3t, b3, (__half*)Hh, N);
    // Stage B+C fused: Yh = agg(Hh) ; Zh = ZSCALE*( [HSCALE*dis*h45] @ W6 ) via LDS tile
    k_spmm<<<sb, 256, 0, stream>>>(Hh, ep, off, dis, Yh, N);
    k_mgemmBC<<<gb, 256, 0, stream>>>((const __half*)Yh, HSCALE_INV, HSCALE, dis,
        W4t, b4, W5t, b5, W6t, Zh, N);
    // Final aggregate + fused tanh/bias -> d_out
    k_spmm64<<<sb, 256, 0, stream>>>(Zh, ep, off, dis, b6, (float*)d_out, N);
}

// Round 14
// 461.172 us; speedup vs baseline: 1.1046x; 1.0234x over previous
//
#include <hip/hip_runtime.h>
#include <hip/hip_bf16.h>
#include <hip/hip_fp16.h>

constexpr int FDIM = 128;
#define HSCALE 16384.0f         // 2^14: |h|<1 -> scaled <16384 <= 65504, always safe
#define HSCALE_INV (1.0f/16384.0f)
#define ZSCALE 0.125f           // extra headroom for Zh = Hh @ W6
#define ZSCALE_COMP (HSCALE_INV * 8.0f)

typedef _Float16 f16x8 __attribute__((ext_vector_type(8)));
typedef float f32x4 __attribute__((ext_vector_type(4)));
typedef unsigned long long ull;

// ===================== atomic-reserved CSR build (2 partition passes) =====================
// record: [col:17 @47][row:17 @30][ew_f16 @0]
// final ep entry (4B): [row:17 @15][f15(norm) @0]   (norm>0 so fp16 sign bit is 0)
constexpr int CHUNK = 4096;
constexpr int B1 = 64;
constexpr int B2 = 64;
constexpr int NGRP = B1 * B2;   // 4096
constexpr int MAXC2 = 20;

__global__ __launch_bounds__(256) void k_init(int* __restrict__ cur1,
                                              int* __restrict__ cur2,
                                              int cap1, int cap2)
{
    int i = blockIdx.x * 256 + threadIdx.x;
    if (i < B1) cur1[i] = i * cap1;
    if (i < NGRP) cur2[i] = i * cap2;
}

// pass 1: chunk -> 64 coarse buckets.
__global__ __launch_bounds__(256) void k_p1part(const int* __restrict__ col,
                                                const int* __restrict__ row,
                                                const float* __restrict__ ew,
                                                int* __restrict__ cur1,
                                                ull* __restrict__ rec1, int E)
{
    __shared__ ull stage[CHUNK];
    __shared__ int hcnt[B1], lb[B1], gb[B1], lcur[B1];
    int blk = blockIdx.x, t = threadIdx.x;
    if (t < B1) hcnt[t] = 0;
    __syncthreads();
    int base = blk * CHUNK;
    ull rc[16];
    #pragma unroll
    for (int it = 0; it < 16; ++it) {
        int g = base + it * 256 + t;
        if (g < E) {
            int c = col[g], r = row[g];
            rc[it] = ((ull)c << 47) | ((ull)r << 30) |
                     (ull)__half_as_ushort(__float2half(ew[g]));
            atomicAdd(&hcnt[c >> 11], 1);
        } else rc[it] = ~0ull;
    }
    __syncthreads();
    if (t == 0) {
        int run = 0;
        for (int b = 0; b < B1; ++b) { lb[b] = run; run += hcnt[b]; }
    }
    __syncthreads();
    if (t < B1) { lcur[t] = lb[t]; gb[t] = atomicAdd(&cur1[t], hcnt[t]); }
    __syncthreads();
    #pragma unroll
    for (int it = 0; it < 16; ++it) {
        if (rc[it] != ~0ull) {
            int b = (int)(rc[it] >> 58);
            stage[atomicAdd(&lcur[b], 1)] = rc[it];
        }
    }
    __syncthreads();
    int here = min(CHUNK, E - base);
    for (int j = t; j < here; j += 256) {
        ull v = stage[j];
        int b = (int)(v >> 58);
        rec1[gb[b] + (j - lb[b])] = v;
    }
}

// pass 2: within each coarse bucket, partition chunks into 64 sub-buckets (groups).
__global__ __launch_bounds__(256) void k_p2part(const ull* __restrict__ rec1,
                                                const int* __restrict__ cur1,
                                                int* __restrict__ cur2,
                                                ull* __restrict__ rec2,
                                                int cap1)
{
    __shared__ ull stage[CHUNK];
    __shared__ int hcnt[B2], lb[B2], gb[B2], lcur[B2];
    int b = blockIdx.x / MAXC2, ci = blockIdx.x % MAXC2, t = threadIdx.x;
    int S1 = b * cap1;
    int size = cur1[b] - S1;
    for (int c = ci; c * CHUNK < size; c += MAXC2) {
        int cb = S1 + c * CHUNK;
        int m = min(CHUNK, size - c * CHUNK);
        __syncthreads();
        if (t < B2) hcnt[t] = 0;
        __syncthreads();
        ull rc[16];
        #pragma unroll
        for (int it = 0; it < 16; ++it) {
            int j = it * 256 + t;
            if (j < m) {
                ull v = rec1[cb + j];
                rc[it] = v;
                atomicAdd(&hcnt[(int)((v >> 52) & 63)], 1);
            } else rc[it] = ~0ull;
        }
        __syncthreads();
        if (t == 0) {
            int run = 0;
            for (int s = 0; s < B2; ++s) { lb[s] = run; run += hcnt[s]; }
        }
        __syncthreads();
        if (t < B2) { lcur[t] = lb[t]; gb[t] = atomicAdd(&cur2[b * B2 + t], hcnt[t]); }
        __syncthreads();
        #pragma unroll
        for (int it = 0; it < 16; ++it) {
            if (rc[it] != ~0ull) {
                int s = (int)((rc[it] >> 52) & 63);
                stage[atomicAdd(&lcur[s], 1)] = rc[it];
            }
        }
        __syncthreads();
        for (int j = t; j < m; j += 256) {
            ull v = stage[j];
            int s = (int)((v >> 52) & 63);
            rec2[gb[s] + (j - lb[s])] = v;
        }
    }
}

// one-block exclusive scan of the 4096 group sizes -> compact output bases
__global__ __launch_bounds__(1024) void k_gscan(const int* __restrict__ cur2,
                                                int* __restrict__ gbase, int cap2)
{
    __shared__ int s[1024];
    __shared__ int carry;
    int t = threadIdx.x;
    if (t == 0) carry = 0;
    __syncthreads();
    for (int tile = 0; tile < 4; ++tile) {
        int g = tile * 1024 + t;
        int v = cur2[g] - g * cap2;
        s[t] = v;
        __syncthreads();
        for (int o = 1; o < 1024; o <<= 1) {
            int u = (t >= o) ? s[t - o] : 0;
            __syncthreads();
            s[t] += u;
            __syncthreads();
        }
        gbase[g] = carry + s[t] - v;    // exclusive
        __syncthreads();
        if (t == 1023) carry += s[t];
        __syncthreads();
    }
}

// final: counting sort per 32-node group; emits compact packed ep, off, dis
__global__ __launch_bounds__(256) void k_p3(const ull* __restrict__ rec2,
                                            const int* __restrict__ cur2,
                                            const int* __restrict__ gbase,
                                            unsigned* __restrict__ ep, int* __restrict__ off,
                                            float* __restrict__ dis, int cap2, int N, int E)
{
    __shared__ int h[32], lb[32], cur[32];
    __shared__ float dg[32], sdis[32];
    int g = blockIdx.x, t = threadIdx.x;
    int S1 = g * cap2;
    int S2 = cur2[g];
    int base = gbase[g];
    if (t < 32) { h[t] = 0; dg[t] = 0.f; }
    __syncthreads();
    for (int i = S1 + t; i < S2; i += 256) {
        ull rc = rec2[i];
        int nl = (int)((rc >> 47) & 31);
        atomicAdd(&h[nl], 1);
        atomicAdd(&dg[nl], __half2float(__ushort_as_half((unsigned short)(rc & 0xFFFF))));
    }
    __syncthreads();
    if (t == 0) {
        int run = base;
        for (int k = 0; k < 32; ++k) { lb[k] = run; run += h[k]; }
    }
    __syncthreads();
    if (t < 32) {
        cur[t] = lb[t];
        sdis[t] = 1.0f / sqrtf(dg[t] + 1.0f);   // self-loop included; >= 1 always
        int node = g * 32 + t;
        if (node < N) { off[node] = lb[t]; dis[node] = sdis[t]; }
    }
    if (g == 0 && t == 0) off[N] = E;
    __syncthreads();
    for (int i = S1 + t; i < S2; i += 256) {
        ull rc = rec2[i];
        int nl = (int)((rc >> 47) & 31);
        int p = atomicAdd(&cur[nl], 1);
        float w = __half2float(__ushort_as_half((unsigned short)(rc & 0xFFFF))) * sdis[nl];
        unsigned rowbits = (unsigned)((rc >> 30) & 0x1FFFF);
        unsigned wbits = (unsigned)__half_as_ushort(__float2half(w));   // sign=0, <=0x7FFF
        ep[p] = (rowbits << 15) | wbits;
    }
}

// unpack f15 norm from packed ep entry
__device__ __forceinline__ float epw(unsigned v) {
    return __half2float(__ushort_as_half((unsigned short)(v & 0x7FFF)));
}

// ---------------- fused prep: h0 f32->f16 with dis pre-scale  +  6 W transposes ----------------
__global__ __launch_bounds__(256) void k_prep(const float4* __restrict__ in,
                                              const float* __restrict__ dis, __half2* __restrict__ out, int n4,
                                              const float* __restrict__ W1, const float* __restrict__ W2,
                                              const float* __restrict__ W3, const float* __restrict__ W4,
                                              const float* __restrict__ W5, const float* __restrict__ W6,
                                              __half* __restrict__ T1, __half* __restrict__ T2,
                                              __half* __restrict__ T3, __half* __restrict__ T4,
                                              __half* __restrict__ T5, __half* __restrict__ T6,
                                              int cvtBlocks)
{
    if ((int)blockIdx.x < cvtBlocks) {
        int i = blockIdx.x * 256 + threadIdx.x;
        if (i >= n4) return;
        float4 v = in[i];
        float d = dis[i >> 5];          // 32 float4 per row
        __half2 a = __floats2half2_rn(v.x * d, v.y * d);
        __half2 b = __floats2half2_rn(v.z * d, v.w * d);
        float2 pk;
        ((__half2*)&pk)[0] = a;
        ((__half2*)&pk)[1] = b;
        *(float2*)&out[(size_t)i * 2] = pk;
    } else {
        int idx = (blockIdx.x - cvtBlocks) * 256 + threadIdx.x;
        const float* W; __half* T; int local, nf;
        if (idx < 81920) {
            int seg = idx >> 14;
            local = idx & 16383;
            nf = 128;
            const float* Ws[5] = {W1, W2, W3, W4, W5};
            __half* Ts[5] = {T1, T2, T3, T4, T5};
            W = Ws[seg]; T = Ts[seg];
        } else if (idx < 90112) {
            local = idx - 81920;
            nf = 64;
            W = W6; T = T6;
        } else return;
        int n = local >> 7, k = local & 127;
        T[local] = __float2half(W[(size_t)k * nf + n]);
    }
}

// ---------------- SpMM: Yh = fp16(aggregate), 4-wide 2-deep (round-8 structure) ----------------
// packed 4B ep; 32-bit gather addressing; non-temporal Yh store.
#define XLD(v) (*(const __half2*)(Xb + ((((v) >> 7) & 0xFFFFFF00u) + loff)))
__global__ __launch_bounds__(256) void k_spmm(const __half2* __restrict__ Xh,
                                              const unsigned* __restrict__ ep,
                                              const int* __restrict__ off,
                                              const float* __restrict__ dis,
                                              __half2* __restrict__ Yh, int n)
{
    int gt = blockIdx.x * 256 + threadIdx.x;
    int node = gt >> 6;
    int lane = threadIdx.x & 63;
    if (node >= n) return;
    const char* Xb = (const char*)Xh;
    const unsigned loff = (unsigned)lane << 2;

    float sn = dis[node];                   // self weight (table already carries one dis)
    float2 x0 = __half22float2(Xh[(size_t)node * 64 + lane]);
    float a0x = sn * x0.x, a0y = sn * x0.y;
    float a1x = 0.f, a1y = 0.f;
    float a2x = 0.f, a2y = 0.f;
    float a3x = 0.f, a3y = 0.f;

    const int e0 = off[node];
    const int cnt = off[node + 1] - e0;
    const unsigned* el = ep + e0;
    const int nb = cnt >> 2;
    int done = 0;

    if (nb >= 2) {
        unsigned q0, q1, q2, q3;
        unsigned p0 = el[0], p1 = el[1], p2 = el[2], p3 = el[3];
        q0 = el[4]; q1 = el[5]; q2 = el[6]; q3 = el[7];
        __half2 xc0 = XLD(p0);
        __half2 xc1 = XLD(p1);
        __half2 xc2 = XLD(p2);
        __half2 xc3 = XLD(p3);
        float wc0 = epw(p0), wc1 = epw(p1);
        float wc2 = epw(p2), wc3 = epw(p3);

        int b;
        #pragma unroll 2
        for (b = 0; b + 2 < nb; ++b) {
            __half2 xn0 = XLD(q0);
            __half2 xn1 = XLD(q1);
            __half2 xn2 = XLD(q2);
            __half2 xn3 = XLD(q3);
            float wn0 = epw(q0), wn1 = epw(q1);
            float wn2 = epw(q2), wn3 = epw(q3);
            const unsigned* eb = el + (size_t)(b + 2) * 4;
            q0 = eb[0]; q1 = eb[1]; q2 = eb[2]; q3 = eb[3];
            float2 f0 = __half22float2(xc0), f1 = __half22float2(xc1);
            float2 f2 = __half22float2(xc2), f3 = __half22float2(xc3);
            a0x += wc0 * f0.x; a0y += wc0 * f0.y;
            a1x += wc1 * f1.x; a1y += wc1 * f1.y;
            a2x += wc2 * f2.x; a2y += wc2 * f2.y;
            a3x += wc3 * f3.x; a3y += wc3 * f3.y;
            xc0 = xn0; xc1 = xn1; xc2 = xn2; xc3 = xn3;
            wc0 = wn0; wc1 = wn1; wc2 = wn2; wc3 = wn3;
        }
        __half2 xn0 = XLD(q0);
        __half2 xn1 = XLD(q1);
        __half2 xn2 = XLD(q2);
        __half2 xn3 = XLD(q3);
        float wn0 = epw(q0), wn1 = epw(q1);
        float wn2 = epw(q2), wn3 = epw(q3);
        {
            float2 f0 = __half22float2(xc0), f1 = __half22float2(xc1);
            float2 f2 = __half22float2(xc2), f3 = __half22float2(xc3);
            a0x += wc0 * f0.x; a0y += wc0 * f0.y;
            a1x += wc1 * f1.x; a1y += wc1 * f1.y;
            a2x += wc2 * f2.x; a2y += wc2 * f2.y;
            a3x += wc3 * f3.x; a3y += wc3 * f3.y;
        }
        {
            float2 f0 = __half22float2(xn0), f1 = __half22float2(xn1);
            float2 f2 = __half22float2(xn2), f3 = __half22float2(xn3);
            a0x += wn0 * f0.x; a0y += wn0 * f0.y;
            a1x += wn1 * f1.x; a1y += wn1 * f1.y;
            a2x += wn2 * f2.x; a2y += wn2 * f2.y;
            a3x += wn3 * f3.x; a3y += wn3 * f3.y;
        }
        done = nb * 4;
    }
    for (int e = done; e < cnt; ++e) {
        unsigned v = el[e];
        float2 xv = __half22float2(XLD(v));
        float w = epw(v);
        a0x += w * xv.x; a0y += w * xv.y;
    }
    float rx = (a0x + a1x) + (a2x + a3x);
    float ry = (a0y + a1y) + (a2y + a3y);
    __half2 r2 = __floats2half2_rn(rx, ry);
    __builtin_nontemporal_store(*(unsigned*)&r2,
                                (unsigned*)(Yh + (size_t)node * 64 + lane));
}
#undef XLD

// ---------------- SpMM64 (stage C): 4 edges per wave-step; packed ep; NT out ----------------
#define ZLD(v) (*(const float2*)(Zb + ((((v) >> 8) & 0xFFFFFF80u) + loff)))
__global__ __launch_bounds__(256) void k_spmm64(const __half* __restrict__ Zh,
                                                const unsigned* __restrict__ ep,
                                                const int* __restrict__ off,
                                                const float* __restrict__ dis,
                                                const float* __restrict__ b6,
                                                float* __restrict__ out, int n)
{
    int gt = blockIdx.x * 256 + threadIdx.x;
    int node = gt >> 6;
    int lane = threadIdx.x & 63;
    if (node >= n) return;
    const int grp = lane >> 4;
    const int l15 = lane & 15;
    const char* Zb = (const char*)Zh;
    const unsigned loff = (unsigned)l15 << 3;    // 8B per lane

    f32x4 acc0 = {0.f, 0.f, 0.f, 0.f};
    f32x4 acc1 = {0.f, 0.f, 0.f, 0.f};

    if (grp == 0) {                              // self-loop term
        float sn = dis[node];
        float2 raw = *(const float2*)(Zb + (((unsigned)node << 7) + loff));
        float2 f0 = __half22float2(((const __half2*)&raw)[0]);
        float2 f1 = __half22float2(((const __half2*)&raw)[1]);
        acc0[0] = sn * f0.x; acc0[1] = sn * f0.y;
        acc0[2] = sn * f1.x; acc0[3] = sn * f1.y;
    }

    const int e0 = off[node];
    const int cnt = off[node + 1] - e0;
    const unsigned* el = ep + e0;
    const int nb = cnt >> 2;                     // batches of 4 edges
    int done = 0;

    if (nb >= 2) {
        unsigned ec = el[grp];
        float2 xc = ZLD(ec);
        unsigned en = el[4 + grp];
        float2 xn;

        #pragma unroll 2
        for (int b = 0; b + 2 < nb; ++b) {
            xn = ZLD(en);
            unsigned e2 = el[(b + 2) * 4 + grp];
            float w = epw(ec);
            float2 f0 = __half22float2(((const __half2*)&xc)[0]);
            float2 f1 = __half22float2(((const __half2*)&xc)[1]);
            if (b & 1) {
                acc1[0] += w * f0.x; acc1[1] += w * f0.y;
                acc1[2] += w * f1.x; acc1[3] += w * f1.y;
            } else {
                acc0[0] += w * f0.x; acc0[1] += w * f0.y;
                acc0[2] += w * f1.x; acc0[3] += w * f1.y;
            }
            ec = en; xc = xn; en = e2;
        }
        // epilogue: batch nb-2 (ec/xc ready) then nb-1 (en, gather now)
        xn = ZLD(en);
        {
            float w = epw(ec);
            float2 f0 = __half22float2(((const __half2*)&xc)[0]);
            float2 f1 = __half22float2(((const __half2*)&xc)[1]);
            acc0[0] += w * f0.x; acc0[1] += w * f0.y;
            acc0[2] += w * f1.x; acc0[3] += w * f1.y;
        }
        {
            float w = epw(en);
            float2 f0 = __half22float2(((const __half2*)&xn)[0]);
            float2 f1 = __half22float2(((const __half2*)&xn)[1]);
            acc1[0] += w * f0.x; acc1[1] += w * f0.y;
            acc1[2] += w * f1.x; acc1[3] += w * f1.y;
        }
        done = nb * 4;
    }
    // tail: 0..3 leftover edges, group-parallel with clamp
    for (int e = done; e < cnt; e += 4) {
        int idx = e + grp;
        unsigned pe = el[min(idx, cnt - 1)];
        float w = (idx < cnt) ? epw(pe) : 0.f;
        float2 raw = ZLD(pe);
        float2 f0 = __half22float2(((const __half2*)&raw)[0]);
        float2 f1 = __half22float2(((const __half2*)&raw)[1]);
        acc0[0] += w * f0.x; acc0[1] += w * f0.y;
        acc0[2] += w * f1.x; acc0[3] += w * f1.y;
    }

    f32x4 r;
    #pragma unroll
    for (int j = 0; j < 4; ++j) {
        r[j] = acc0[j] + acc1[j];
        r[j] += __shfl_xor(r[j], 16);
        r[j] += __shfl_xor(r[j], 32);
    }
    if (lane < 16) {
        float4 bb = *(const float4*)(b6 + 4 * l15);
        f32x4 o;
        o[0] = tanhf(fmaf(r[0], ZSCALE_COMP, bb.x));
        o[1] = tanhf(fmaf(r[1], ZSCALE_COMP, bb.y));
        o[2] = tanhf(fmaf(r[2], ZSCALE_COMP, bb.z));
        o[3] = tanhf(fmaf(r[3], ZSCALE_COMP, bb.w));
        __builtin_nontemporal_store(o,
            (f32x4*)((char*)out + (((size_t)node << 8) + ((unsigned)l15 << 4))));
    }
}
#undef ZLD

// fast tanh: 1 - 2/(e^{2x}+1) via v_exp + v_rcp
__device__ __forceinline__ float fast_tanh(float x) {
    float e = __expf(2.0f * x);
    return 1.0f - 2.0f * __builtin_amdgcn_rcpf(e + 1.0f);
}

// ---------------- MFMA GEMM, register-resident B (round-8 proven; stage A only) ----------------
template <int FOUT, int NW, bool ACT>
__global__ __launch_bounds__(256, 2) void k_mgemm(const __half* __restrict__ Yh,
                                                  float IS, float OS,
                                                  const float* __restrict__ dis,
                                                  const __half* __restrict__ Wt0, const float* __restrict__ B0,
                                                  const __half* __restrict__ Wt1, const float* __restrict__ B1,
                                                  const __half* __restrict__ Wt2, const float* __restrict__ B2,
                                                  __half* __restrict__ Out, int nRows)
{
    constexpr int NF = FOUT / 16;
    constexpr int FPW = NF / 4;
    int tid = threadIdx.x;
    int wv = tid >> 6;
    int lane = tid & 63;
    int lo = lane & 15, hi = lane >> 4;
    int r0 = blockIdx.x * 64;

    const __half* Wts[3] = {Wt0, Wt1, Wt2};
    const float*  Bs[3]  = {B0, B1, B2};

    f16x8 bfr[FPW][NW][4];
    float bias[FPW][NW];
    #pragma unroll
    for (int fp = 0; fp < FPW; ++fp) {
        int f = wv * FPW + fp;
        #pragma unroll
        for (int w = 0; w < NW; ++w) {
            const __half* Bp = Wts[w] + (size_t)(f * 16 + lo) * 128 + hi * 8;
            #pragma unroll
            for (int ks = 0; ks < 4; ++ks)
                bfr[fp][w][ks] = *(const f16x8*)(Bp + ks * 32);
            if constexpr (ACT) bias[fp][w] = Bs[w][f * 16 + lo];
        }
    }

    float disr[4][4];
    if constexpr (ACT) {
        #pragma unroll
        for (int rt = 0; rt < 4; ++rt)
            #pragma unroll
            for (int r = 0; r < 4; ++r) {
                int row = r0 + rt * 16 + hi * 4 + r;
                if (row >= nRows) row = nRows - 1;
                disr[rt][r] = dis[row];
            }
    }

    f16x8 a[4], an[4];
    {
        int row = r0 + lo;
        if (row >= nRows) row = nRows - 1;
        const __half* Ap = Yh + (size_t)row * 128 + hi * 8;
        #pragma unroll
        for (int ks = 0; ks < 4; ++ks) a[ks] = *(const f16x8*)(Ap + ks * 32);
    }

    #pragma unroll
    for (int rt = 0; rt < 4; ++rt) {
        if (rt < 3) {
            int row = r0 + (rt + 1) * 16 + lo;
            if (row >= nRows) row = nRows - 1;
            const __half* Ap = Yh + (size_t)row * 128 + hi * 8;
            #pragma unroll
            for (int ks = 0; ks < 4; ++ks) an[ks] = *(const f16x8*)(Ap + ks * 32);
        }
        #pragma unroll
        for (int fp = 0; fp < FPW; ++fp) {
            f32x4 ac0 = {0.f, 0.f, 0.f, 0.f};
            f32x4 ac1 = {0.f, 0.f, 0.f, 0.f};
            f32x4 ac2 = {0.f, 0.f, 0.f, 0.f};
            #pragma unroll
            for (int ks = 0; ks < 4; ++ks) {
                ac0 = __builtin_amdgcn_mfma_f32_16x16x32_f16(a[ks], bfr[fp][0][ks], ac0, 0, 0, 0);
                if constexpr (NW > 1)
                    ac1 = __builtin_amdgcn_mfma_f32_16x16x32_f16(a[ks], bfr[fp][1][ks], ac1, 0, 0, 0);
                if constexpr (NW > 2)
                    ac2 = __builtin_amdgcn_mfma_f32_16x16x32_f16(a[ks], bfr[fp][2][ks], ac2, 0, 0, 0);
            }
            int c = (wv * FPW + fp) * 16 + lo;
            #pragma unroll
            for (int r = 0; r < 4; ++r) {
                int row = r0 + rt * 16 + hi * 4 + r;
                float v;
                if constexpr (ACT) {
                    v = fast_tanh(fmaf(ac0[r], IS, bias[fp][0]));
                    if constexpr (NW > 1) v *= fast_tanh(fmaf(ac1[r], IS, bias[fp][1]));
                    if constexpr (NW > 2) v *= fast_tanh(fmaf(ac2[r], IS, bias[fp][2]));
                    v *= OS * disr[rt][r];
                } else {
                    v = ac0[r] * OS;
                }
                if (row < nRows)
                    Out[(size_t)row * FOUT + c] = __float2half(v);
            }
        }
        #pragma unroll
        for (int ks = 0; ks < 4; ++ks) a[ks] = an[ks];
    }
}

// ---------------- Fused stage B+C: h45 GEMM (NW=2, tanh-product) -> LDS -> @W6 -> Zh ----------------
__global__ __launch_bounds__(256, 2) void k_mgemmBC(const __half* __restrict__ Yh,
                                                    float IS, float OS,
                                                    const float* __restrict__ dis,
                                                    const __half* __restrict__ Wt0, const float* __restrict__ B0,
                                                    const __half* __restrict__ Wt1, const float* __restrict__ B1,
                                                    const __half* __restrict__ Wt6,
                                                    __half* __restrict__ Zh, int nRows)
{
    constexpr int LDH = 136;
    __shared__ __half tile[64 * LDH];
    int tid = threadIdx.x;
    int wv = tid >> 6;
    int lane = tid & 63;
    int lo = lane & 15, hi = lane >> 4;
    int r0 = blockIdx.x * 64;

    const __half* Wts[2] = {Wt0, Wt1};
    const float*  Bs[2]  = {B0, B1};

    f16x8 bfr[2][2][4];
    float bias[2][2];
    #pragma unroll
    for (int fp = 0; fp < 2; ++fp) {
        int f = wv * 2 + fp;
        #pragma unroll
        for (int w = 0; w < 2; ++w) {
            const __half* Bp = Wts[w] + (size_t)(f * 16 + lo) * 128 + hi * 8;
            #pragma unroll
            for (int ks = 0; ks < 4; ++ks)
                bfr[fp][w][ks] = *(const f16x8*)(Bp + ks * 32);
            bias[fp][w] = Bs[w][f * 16 + lo];
        }
    }

    float disr[4][4];
    #pragma unroll
    for (int rt = 0; rt < 4; ++rt)
        #pragma unroll
        for (int r = 0; r < 4; ++r) {
            int row = r0 + rt * 16 + hi * 4 + r;
            if (row >= nRows) row = nRows - 1;
            disr[rt][r] = dis[row];
        }

    f16x8 a[4], an[4];
    {
        int row = r0 + lo;
        if (row >= nRows) row = nRows - 1;
        const __half* Ap = Yh + (size_t)row * 128 + hi * 8;
        #pragma unroll
        for (int ks = 0; ks < 4; ++ks) a[ks] = *(const f16x8*)(Ap + ks * 32);
    }

    #pragma unroll
    for (int rt = 0; rt < 4; ++rt) {
        if (rt < 3) {
            int row = r0 + (rt + 1) * 16 + lo;
            if (row >= nRows) row = nRows - 1;
            const __half* Ap = Yh + (size_t)row * 128 + hi * 8;
            #pragma unroll
            for (int ks = 0; ks < 4; ++ks) an[ks] = *(const f16x8*)(Ap + ks * 32);
        }
        #pragma unroll
        for (int fp = 0; fp < 2; ++fp) {
            f32x4 ac0 = {0.f, 0.f, 0.f, 0.f};
            f32x4 ac1 = {0.f, 0.f, 0.f, 0.f};
            #pragma unroll
            for (int ks = 0; ks < 4; ++ks) {
                ac0 = __builtin_amdgcn_mfma_f32_16x16x32_f16(a[ks], bfr[fp][0][ks], ac0, 0, 0, 0);
                ac1 = __builtin_amdgcn_mfma_f32_16x16x32_f16(a[ks], bfr[fp][1][ks], ac1, 0, 0, 0);
            }
            int c = (wv * 2 + fp) * 16 + lo;
            #pragma unroll
            for (int r = 0; r < 4; ++r) {
                float v = fast_tanh(fmaf(ac0[r], IS, bias[fp][0]))
                        * fast_tanh(fmaf(ac1[r], IS, bias[fp][1]));
                v *= OS * disr[rt][r];
                tile[(rt * 16 + hi * 4 + r) * LDH + c] = __float2half(v);
            }
        }
        #pragma unroll
        for (int ks = 0; ks < 4; ++ks) a[ks] = an[ks];
    }
    __syncthreads();

    // phase 2: Zh = ZSCALE * tile @ W6t
    f16x8 b6f[4];
    {
        const __half* Bp = Wt6 + (size_t)(wv * 16 + lo) * 128 + hi * 8;
        #pragma unroll
        for (int ks = 0; ks < 4; ++ks) b6f[ks] = *(const f16x8*)(Bp + ks * 32);
    }
    int c2 = wv * 16 + lo;
    #pragma unroll
    for (int rt = 0; rt < 4; ++rt) {
        f16x8 a2[4];
        const __half* Tp = &tile[(rt * 16 + lo) * LDH + hi * 8];
        #pragma unroll
        for (int ks = 0; ks < 4; ++ks) a2[ks] = *(const f16x8*)(Tp + ks * 32);
        f32x4 acc = {0.f, 0.f, 0.f, 0.f};
        #pragma unroll
        for (int ks = 0; ks < 4; ++ks)
            acc = __builtin_amdgcn_mfma_f32_16x16x32_f16(a2[ks], b6f[ks], acc, 0, 0, 0);
        #pragma unroll
        for (int r = 0; r < 4; ++r) {
            int row = r0 + rt * 16 + hi * 4 + r;
            if (row < nRows)
                Zh[(size_t)row * 64 + c2] = __float2half(acc[r] * ZSCALE);
        }
    }
}

extern "C" void kernel_launch(void* const* d_in, const int* in_sizes, int n_in,
                              void* d_out, int out_size, void* d_ws, size_t ws_size,
                              hipStream_t stream)
{
    const float* h0 = (const float*)d_in[0];
    const int*   ei = (const int*)d_in[1];
    const float* ew = (const float*)d_in[2];
    const float* W1 = (const float*)d_in[3];  const float* b1 = (const float*)d_in[4];
    const float* W2 = (const float*)d_in[5];  const float* b2 = (const float*)d_in[6];
    const float* W3 = (const float*)d_in[7];  const float* b3 = (const float*)d_in[8];
    const float* W4 = (const float*)d_in[9];  const float* b4 = (const float*)d_in[10];
    const float* W5 = (const float*)d_in[11]; const float* b5 = (const float*)d_in[12];
    const float* W6 = (const float*)d_in[13]; const float* b6 = (const float*)d_in[14];

    const int N = in_sizes[0] / FDIM;
    const int E = in_sizes[2];
    const int* rowp = ei;
    const int* colp = ei + E;

    const int NB1 = (E + CHUNK - 1) / CHUNK;
    const int cap1 = E / 40;        // 80000 for E=3.2M (mean 65.5K)
    const int cap2 = E / 2000;      // 1600 for E=3.2M (mean 1024)

    char* p = (char*)d_ws;
    auto alloc = [&](size_t bytes) -> void* {
        void* r = (void*)p;
        p += (bytes + 255) & ~(size_t)255;
        return r;
    };
    int* cur1  = (int*)alloc((size_t)B1 * 4);
    int* cur2  = (int*)alloc((size_t)NGRP * 4);
    int* gbase = (int*)alloc((size_t)(NGRP + 1) * 4);
    int* off   = (int*)alloc((size_t)(N + 1) * 4);
    float* dis = (float*)alloc((size_t)N * 4);
    ull* rec1  = (ull*)alloc((size_t)B1 * cap1 * 8);    // later aliased by ep (4B, smaller)
    ull* rec2  = (ull*)alloc((size_t)NGRP * cap2 * 8);  // later aliased by Yh
    __half2* Xh = (__half2*)alloc((size_t)N * FDIM * 2);  // later aliased by Zh
    __half2* Hh = (__half2*)alloc((size_t)N * FDIM * 2);
    __half* W1t = (__half*)alloc((size_t)128 * 128 * 2);
    __half* W2t = (__half*)alloc((size_t)128 * 128 * 2);
    __half* W3t = (__half*)alloc((size_t)128 * 128 * 2);
    __half* W4t = (__half*)alloc((size_t)128 * 128 * 2);
    __half* W5t = (__half*)alloc((size_t)128 * 128 * 2);
    __half* W6t = (__half*)alloc((size_t)64 * 128 * 2);

    unsigned* ep = (unsigned*)rec1;  // rec1 dead after k_p2part
    __half2*  Yh = (__half2*)rec2;   // rec2 dead after k_p3
    __half*   Zh = (__half*)Xh;      // Xh dead after stage-A spmm

    // ---- build (round-11 proven: gscan-based compact bases) ----
    k_init<<<(NGRP + 255) / 256, 256, 0, stream>>>(cur1, cur2, cap1, cap2);
    k_p1part<<<NB1, 256, 0, stream>>>(colp, rowp, ew, cur1, rec1, E);
    k_p2part<<<B1 * MAXC2, 256, 0, stream>>>(rec1, cur1, cur2, rec2, cap1);
    k_gscan<<<1, 1024, 0, stream>>>(cur2, gbase, cap2);
    k_p3<<<NGRP, 256, 0, stream>>>(rec2, cur2, gbase, ep, off, dis, cap2, N, E);

    // ---- fused dense prep (cvt + all weight transposes) ----
    const int cvtBlocks = (N * 32 + 255) / 256;
    k_prep<<<cvtBlocks + 352, 256, 0, stream>>>((const float4*)h0, dis, Xh, N * 32,
        W1, W2, W3, W4, W5, W6, W1t, W2t, W3t, W4t, W5t, W6t, cvtBlocks);

    const int sb = (N + 3) / 4;     // 4 waves (nodes) per 256-thread block
    const int gb = (N + 63) / 64;   // 64-row tiles

    // Stage A: Yh = agg(Xh) ; Hh = HSCALE*dis*tanh(YhW1+b1)*tanh(YhW2+b2)*tanh(YhW3+b3)
    k_spmm<<<sb, 256, 0, stream>>>(Xh, ep, off, dis, Yh, N);
    k_mgemm<128, 3, true><<<gb, 256, 0, stream>>>((const __half*)Yh, 1.0f, HSCALE, dis,
        W1t, b1, W2t, b2, W3t, b3, (__half*)Hh, N);
    // Stage B+C fused: Yh = agg(Hh) ; Zh = ZSCALE*( [HSCALE*dis*h45] @ W6 ) via LDS tile
    k_spmm<<<sb, 256, 0, stream>>>(Hh, ep, off, dis, Yh, N);
    k_mgemmBC<<<gb, 256, 0, stream>>>((const __half*)Yh, HSCALE_INV, HSCALE, dis,
        W4t, b4, W5t, b5, W6t, Zh, N);
    // Final aggregate + fused tanh/bias -> d_out
    k_spmm64<<<sb, 256, 0, stream>>>(Zh, ep, off, dis, b6, (float*)d_out, N);
}